// Round 3
// baseline (246.709 us; speedup 1.0000x reference)
//
#include <hip/hip_runtime.h>

#define L_SEQ 8192
#define DIMN  2048
#define CHUNK 32
#define NCHUNK (L_SEQ / CHUNK)   // 256

typedef float  f32x4  __attribute__((ext_vector_type(4)));
typedef __bf16 bf16x8 __attribute__((ext_vector_type(8)));

__device__ __forceinline__ unsigned short f2bf(float f) {
    unsigned int u = __float_as_uint(f);
    u += 0x7fffu + ((u >> 16) & 1u);          // round-to-nearest-even
    return (unsigned short)(u >> 16);
}
__device__ __forceinline__ float bf2f(unsigned short u) {
    return __uint_as_float((unsigned int)u << 16);
}
__device__ __forceinline__ float sigmoidf_(float v) {
    return 1.0f / (1.0f + __expf(-v));
}

// ---- Pass 1 (fused): local chunk scans with h_in=0 (blocks 0..511) writing
// bf16 local result + fp32 carry, plus W fp32->bf16 (blocks 512..1023).
__global__ void stage1(const float* __restrict__ x, const float* __restrict__ fp,
                       const float* __restrict__ W,
                       float* __restrict__ carryA, unsigned short* __restrict__ xmix,
                       unsigned short* __restrict__ Wb) {
    int b = blockIdx.x;
    if (b < 512) {
        int cg = b & 1;                       // channel group (1024 ch each)
        int c  = b >> 1;                      // chunk [0,256)
        int d4 = cg * 256 + threadIdx.x;      // float4 channel index
        float4 f4 = ((const float4*)fp)[d4];
        float fa = sigmoidf_(f4.x), fb = sigmoidf_(f4.y),
              fc = sigmoidf_(f4.z), fd = sigmoidf_(f4.w);
        float ga = 1.f - fa, gb = 1.f - fb, gc = 1.f - fc, gd = 1.f - fd;
        float ha = 0.f, hb = 0.f, hc = 0.f, hd = 0.f;
        const float4* xp = (const float4*)x + (size_t)c * CHUNK * (DIMN / 4) + d4;
        ushort4* lp = (ushort4*)xmix + (size_t)c * CHUNK * (DIMN / 4) + d4;
#pragma unroll 8
        for (int t = 0; t < CHUNK; ++t) {
            float4 v = xp[(size_t)t * (DIMN / 4)];
            ha = fmaf(fa, ha, ga * v.x);
            hb = fmaf(fb, hb, gb * v.y);
            hc = fmaf(fc, hc, gc * v.z);
            hd = fmaf(fd, hd, gd * v.w);
            ushort4 o; o.x = f2bf(ha); o.y = f2bf(hb); o.z = f2bf(hc); o.w = f2bf(hd);
            lp[(size_t)t * (DIMN / 4)] = o;
        }
        ((float4*)(carryA + (size_t)c * DIMN))[d4] = (float4){ha, hb, hc, hd};
    } else {
#pragma unroll
        for (int k = 0; k < 8; ++k) {
            int i = (b - 512) * 2048 + k * 256 + threadIdx.x;   // float4 index into W
            float4 v = ((const float4*)W)[i];
            ushort4 o;
            o.x = f2bf(v.x); o.y = f2bf(v.y); o.z = f2bf(v.z); o.w = f2bf(v.w);
            ((ushort4*)Wb)[i] = o;
        }
    }
}

// ---- Pass 2: sequential prefix over 256 chunks; carryB[c][d] = h_in(chunk c) ----
__global__ void carry_prefix(const float* __restrict__ fp, const float* __restrict__ xml,
                             const float* __restrict__ carryA, float* __restrict__ carryB) {
    int d = blockIdx.x * 256 + threadIdx.x;       // 8 blocks x 256 = 2048 channels
    float f = sigmoidf_(fp[d]);
    float fC = f;                                  // f^32 via 5 squarings
    fC *= fC; fC *= fC; fC *= fC; fC *= fC; fC *= fC;
    float h = xml[d];                              // h[-1] = x_mix_last
#pragma unroll 8
    for (int c = 0; c < NCHUNK; ++c) {
        float lv = carryA[(size_t)c * DIMN + d];
        carryB[(size_t)c * DIMN + d] = h;
        h = fmaf(fC, h, lv);
    }
}

// ---- Pass 3: elementwise correction, in place: xmix += H * f^(t+1) ----
__global__ void apply_corr(const float* __restrict__ fp, const float* __restrict__ carryB,
                           unsigned short* __restrict__ xmix) {
    int b = blockIdx.x;
    int cg = b & 1;
    int c  = b >> 1;
    int d4 = cg * 256 + threadIdx.x;
    float4 f4 = ((const float4*)fp)[d4];
    float fa = sigmoidf_(f4.x), fb = sigmoidf_(f4.y),
          fc = sigmoidf_(f4.z), fd = sigmoidf_(f4.w);
    float4 H = ((const float4*)(carryB + (size_t)c * DIMN))[d4];
    float pa = fa, pb = fb, pc = fc, pd = fd;      // f^(t+1), t=0 -> f
    ushort4* lp = (ushort4*)xmix + (size_t)c * CHUNK * (DIMN / 4) + d4;
#pragma unroll 8
    for (int t = 0; t < CHUNK; ++t) {
        ushort4 u = lp[(size_t)t * (DIMN / 4)];
        ushort4 o;
        o.x = f2bf(fmaf(H.x, pa, bf2f(u.x)));
        o.y = f2bf(fmaf(H.y, pb, bf2f(u.y)));
        o.z = f2bf(fmaf(H.z, pc, bf2f(u.z)));
        o.w = f2bf(fmaf(H.w, pd, bf2f(u.w)));
        lp[(size_t)t * (DIMN / 4)] = o;
        pa *= fa; pb *= fb; pc *= fc; pd *= fd;
    }
}

// ---- GEMM: C[M][N] = A[M][K] * B[N][K]^T, bf16 in / fp32 out ----
// 128x128 tile, BK=64, 4 waves, each wave 64x64 (4x4 of 16x16x32 MFMA).
// LDS k-slot XOR-swizzled (slot = c ^ (row&7)): zero bank conflicts (R2 measured).
// Grid: x = tn (16), y = tm (64) -> consecutive blocks share the A-slab (L2 reuse).
__global__ __launch_bounds__(256) void gemm_bt(
        const unsigned short* __restrict__ A,
        const unsigned short* __restrict__ B,
        float* __restrict__ C) {
    constexpr int N_ = DIMN, K_ = DIMN;
    constexpr int BK = 64;
    __shared__ __align__(16) unsigned short As[128 * BK];
    __shared__ __align__(16) unsigned short Bs[128 * BK];

    int tid  = threadIdx.x;
    int wave = tid >> 6;
    int lane = tid & 63;
    int quad = lane >> 4;
    int l16  = lane & 15;
    int tn = blockIdx.x, tm = blockIdx.y;
    int wm = wave >> 1, wn = wave & 1;

    f32x4 acc[4][4];
#pragma unroll
    for (int i = 0; i < 4; ++i)
#pragma unroll
        for (int j = 0; j < 4; ++j)
            acc[i][j] = (f32x4){0.f, 0.f, 0.f, 0.f};

    const unsigned short* aBase = A + (size_t)(tm * 128) * K_;
    const unsigned short* bBase = B + (size_t)(tn * 128) * K_;

    for (int k0 = 0; k0 < K_; k0 += BK) {
#pragma unroll
        for (int i = 0; i < 4; ++i) {
            int idx = i * 256 + tid;          // 16B-chunk index, [0,1024)
            int row = idx >> 3, slot = idx & 7;
            int cc = slot ^ (row & 7);
            __builtin_amdgcn_global_load_lds(
                (const __attribute__((address_space(1))) void*)(aBase + (size_t)row * K_ + k0 + cc * 8),
                (__attribute__((address_space(3))) void*)(As + idx * 8), 16, 0, 0);
        }
#pragma unroll
        for (int i = 0; i < 4; ++i) {
            int idx = i * 256 + tid;
            int row = idx >> 3, slot = idx & 7;
            int cc = slot ^ (row & 7);
            __builtin_amdgcn_global_load_lds(
                (const __attribute__((address_space(1))) void*)(bBase + (size_t)row * K_ + k0 + cc * 8),
                (__attribute__((address_space(3))) void*)(Bs + idx * 8), 16, 0, 0);
        }
        __syncthreads();

#pragma unroll
        for (int kk = 0; kk < BK; kk += 32) {
            bf16x8 af[4], bg[4];
#pragma unroll
            for (int i = 0; i < 4; ++i) {
                int r = wm * 64 + i * 16 + l16;
                int c0 = (kk >> 3) + quad;
                af[i] = *(const bf16x8*)(As + r * BK + ((c0 ^ (r & 7)) << 3));
            }
#pragma unroll
            for (int j = 0; j < 4; ++j) {
                int r = wn * 64 + j * 16 + l16;
                int c0 = (kk >> 3) + quad;
                bg[j] = *(const bf16x8*)(Bs + r * BK + ((c0 ^ (r & 7)) << 3));
            }
#pragma unroll
            for (int i = 0; i < 4; ++i)
#pragma unroll
                for (int j = 0; j < 4; ++j)
                    acc[i][j] = __builtin_amdgcn_mfma_f32_16x16x32_bf16(af[i], bg[j], acc[i][j], 0, 0, 0);
        }
        __syncthreads();
    }

    // Epilogue: C/D layout col = lane&15, row = quad*4 + reg.
#pragma unroll
    for (int i = 0; i < 4; ++i) {
#pragma unroll
        for (int j = 0; j < 4; ++j) {
            int col = tn * 128 + wn * 64 + j * 16 + l16;
#pragma unroll
            for (int r = 0; r < 4; ++r) {
                int row = tm * 128 + wm * 64 + i * 16 + quad * 4 + r;
                C[(size_t)row * N_ + col] = acc[i][j][r];
            }
        }
    }
}

extern "C" void kernel_launch(void* const* d_in, const int* in_sizes, int n_in,
                              void* d_out, int out_size, void* d_ws, size_t ws_size,
                              hipStream_t stream) {
    const float* x   = (const float*)d_in[0];   // [L, D]
    const float* xml = (const float*)d_in[1];   // [D]
    const float* fp  = (const float*)d_in[2];   // [D]
    const float* W   = (const float*)d_in[3];   // [D, D]
    float* out = (float*)d_out;                 // [L, D] fp32

    unsigned short* xmix = (unsigned short*)d_ws;                                      // 32 MB
    unsigned short* Wb   = (unsigned short*)((char*)d_ws + (size_t)L_SEQ * DIMN * 2);  // 8 MB
    float* carryA = (float*)((char*)d_ws + 40ull * 1024 * 1024);                       // 2 MB
    float* carryB = (float*)((char*)d_ws + 42ull * 1024 * 1024);                       // 2 MB

    stage1<<<1024, 256, 0, stream>>>(x, fp, W, carryA, xmix, Wb);
    carry_prefix<<<DIMN / 256, 256, 0, stream>>>(fp, xml, carryA, carryB);
    apply_corr<<<512, 256, 0, stream>>>(fp, carryB, xmix);
    gemm_bt<<<dim3(DIMN / 128, L_SEQ / 128), 256, 0, stream>>>(xmix, Wb, out);
}

// Round 5
// 203.235 us; speedup vs baseline: 1.2139x; 1.2139x over previous
//
#include <hip/hip_runtime.h>

#define L_SEQ 8192
#define DIMN  2048
#define CHUNK 64
#define NCHUNK (L_SEQ / CHUNK)   // 128

typedef float  f32x4  __attribute__((ext_vector_type(4)));
typedef __bf16 bf16x8 __attribute__((ext_vector_type(8)));

__device__ __forceinline__ unsigned short f2bf(float f) {
    unsigned int u = __float_as_uint(f);
    u += 0x7fffu + ((u >> 16) & 1u);          // round-to-nearest-even
    return (unsigned short)(u >> 16);
}

__device__ __forceinline__ float sigmoidf_(float v) {
    return 1.0f / (1.0f + __expf(-v));
}

// ---- Stage 1 (fused): local chunk scans (blocks 0..255) + W fp32->bf16 (blocks 256..4351)
__global__ void stage1(const float* __restrict__ x, const float* __restrict__ fp,
                       const float* __restrict__ W,
                       float* __restrict__ carry, unsigned short* __restrict__ Wb) {
    int b = blockIdx.x;
    if (b < 256) {
        // per-(chunk, 4-channel) local scan with h_in = 0; store carry.
        int cg = b & 1;                       // channel group (1024 ch each)
        int c  = b >> 1;                      // chunk
        int d4 = cg * 256 + threadIdx.x;      // float4 channel index
        float4 f4 = ((const float4*)fp)[d4];
        float fa = sigmoidf_(f4.x), fb = sigmoidf_(f4.y),
              fc = sigmoidf_(f4.z), fd = sigmoidf_(f4.w);
        float ga = 1.f - fa, gb = 1.f - fb, gc = 1.f - fc, gd = 1.f - fd;
        float ha = 0.f, hb = 0.f, hc = 0.f, hd = 0.f;
        const float4* xp = (const float4*)(x + (size_t)c * CHUNK * DIMN) + d4;
#pragma unroll 8
        for (int t = 0; t < CHUNK; ++t) {
            float4 v = xp[(size_t)t * (DIMN / 4)];
            ha = fmaf(fa, ha, ga * v.x);
            hb = fmaf(fb, hb, gb * v.y);
            hc = fmaf(fc, hc, gc * v.z);
            hd = fmaf(fd, hd, gd * v.w);
        }
        ((float4*)(carry + (size_t)c * DIMN))[d4] = (float4){ha, hb, hc, hd};
    } else {
        int i = (b - 256) * 256 + threadIdx.x;     // float4 index into W
        float4 v = ((const float4*)W)[i];
        ushort4 o;
        o.x = f2bf(v.x); o.y = f2bf(v.y); o.z = f2bf(v.z); o.w = f2bf(v.w);
        ((ushort4*)Wb)[i] = o;
    }
}

// ---- Stage 2: sequential prefix over chunks, all carries held in VGPRs ----
__global__ __launch_bounds__(64) void carry_prefix(const float* __restrict__ fp,
                                                   const float* __restrict__ xml,
                                                   float* __restrict__ carry) {
    int d = blockIdx.x * 64 + threadIdx.x;        // one channel per lane
    float f = sigmoidf_(fp[d]);
    float fC = f;                                  // f^64 via 6 squarings
    fC *= fC; fC *= fC; fC *= fC; fC *= fC; fC *= fC; fC *= fC;
    float v[NCHUNK];
#pragma unroll
    for (int c = 0; c < NCHUNK; ++c) v[c] = carry[(size_t)c * DIMN + d];
    float h = xml[d];
#pragma unroll
    for (int c = 0; c < NCHUNK; ++c) {
        carry[(size_t)c * DIMN + d] = h;           // h_in for chunk c
        h = fmaf(fC, h, v[c]);
    }
}

// ---- Stage 3: re-scan with correct h_in, emit x_mix as bf16 ----
__global__ void scan_apply(const float* __restrict__ x, const float* __restrict__ fp,
                           const float* __restrict__ carry, unsigned short* __restrict__ xmix) {
    int b = blockIdx.x;
    int cg = b & 1;
    int c  = b >> 1;
    int d4 = cg * 256 + threadIdx.x;
    float4 f4 = ((const float4*)fp)[d4];
    float fa = sigmoidf_(f4.x), fb = sigmoidf_(f4.y),
          fc = sigmoidf_(f4.z), fd = sigmoidf_(f4.w);
    float ga = 1.f - fa, gb = 1.f - fb, gc = 1.f - fc, gd = 1.f - fd;
    float4 h0 = ((const float4*)(carry + (size_t)c * DIMN))[d4];
    float ha = h0.x, hb = h0.y, hc = h0.z, hd = h0.w;
    const float4* xp = (const float4*)(x + (size_t)c * CHUNK * DIMN) + d4;
    ushort4* op = (ushort4*)(xmix + (size_t)c * CHUNK * DIMN) + d4;
#pragma unroll 8
    for (int t = 0; t < CHUNK; ++t) {
        float4 v = xp[(size_t)t * (DIMN / 4)];
        ha = fmaf(fa, ha, ga * v.x);
        hb = fmaf(fb, hb, gb * v.y);
        hc = fmaf(fc, hc, gc * v.z);
        hd = fmaf(fd, hd, gd * v.w);
        ushort4 o; o.x = f2bf(ha); o.y = f2bf(hb); o.z = f2bf(hc); o.w = f2bf(hd);
        op[(size_t)t * (DIMN / 4)] = o;
    }
}

// ---- GEMM: C[M][N] = A[M][K] * B[N][K]^T, bf16 in / fp32 out ----
// 128x256 block tile, BK=64, 4 waves, each wave 64x128 (4x8 of 16x16x32 MFMA):
// 12 ds_read_b128 feed 32 MFMAs per k-step -> MFMA-bound, not LDS-read-bound.
// A-tile = 128x64 bf16 = 1024 16B-chunks (4 staging iters x 256 threads);
// B-tile = 256x64 bf16 = 2048 chunks (8 iters).   (R4 bug: halved both -> poison)
// LDS k-slot XOR-swizzled (slot ^ (row&7)): zero bank conflicts (R2 measured).
// Grid: x = tm (fastest) -> consecutive blocks share the B-slab.
__global__ __launch_bounds__(256, 2) void gemm_bt(
        const unsigned short* __restrict__ A,
        const unsigned short* __restrict__ B,
        float* __restrict__ C) {
    constexpr int N_ = DIMN, K_ = DIMN;
    constexpr int BK = 64;
    __shared__ __align__(16) unsigned short As[128 * BK];   // 16 KB
    __shared__ __align__(16) unsigned short Bs[256 * BK];   // 32 KB

    int tid  = threadIdx.x;
    int wave = tid >> 6;
    int lane = tid & 63;
    int quad = lane >> 4;
    int l16  = lane & 15;
    int tm = blockIdx.x, tn = blockIdx.y;
    int wm = wave >> 1, wn = wave & 1;

    f32x4 acc[4][8];
#pragma unroll
    for (int i = 0; i < 4; ++i)
#pragma unroll
        for (int j = 0; j < 8; ++j)
            acc[i][j] = (f32x4){0.f, 0.f, 0.f, 0.f};

    const unsigned short* aBase = A + (size_t)(tm * 128) * K_;
    const unsigned short* bBase = B + (size_t)(tn * 256) * K_;

    for (int k0 = 0; k0 < K_; k0 += BK) {
#pragma unroll
        for (int i = 0; i < 4; ++i) {
            int idx = i * 256 + tid;          // A: 1024 chunks
            int row = idx >> 3, slot = idx & 7;
            int cc = slot ^ (row & 7);
            __builtin_amdgcn_global_load_lds(
                (const __attribute__((address_space(1))) void*)(aBase + (size_t)row * K_ + k0 + cc * 8),
                (__attribute__((address_space(3))) void*)(As + idx * 8), 16, 0, 0);
        }
#pragma unroll
        for (int i = 0; i < 8; ++i) {
            int idx = i * 256 + tid;          // B: 2048 chunks
            int row = idx >> 3, slot = idx & 7;
            int cc = slot ^ (row & 7);
            __builtin_amdgcn_global_load_lds(
                (const __attribute__((address_space(1))) void*)(bBase + (size_t)row * K_ + k0 + cc * 8),
                (__attribute__((address_space(3))) void*)(Bs + idx * 8), 16, 0, 0);
        }
        __syncthreads();

#pragma unroll
        for (int kk = 0; kk < BK; kk += 32) {
            bf16x8 af[4], bg[8];
#pragma unroll
            for (int i = 0; i < 4; ++i) {
                int r = wm * 64 + i * 16 + l16;
                int c0 = (kk >> 3) + quad;
                af[i] = *(const bf16x8*)(As + r * BK + ((c0 ^ (r & 7)) << 3));
            }
#pragma unroll
            for (int j = 0; j < 8; ++j) {
                int r = wn * 128 + j * 16 + l16;
                int c0 = (kk >> 3) + quad;
                bg[j] = *(const bf16x8*)(Bs + r * BK + ((c0 ^ (r & 7)) << 3));
            }
#pragma unroll
            for (int i = 0; i < 4; ++i)
#pragma unroll
                for (int j = 0; j < 8; ++j)
                    acc[i][j] = __builtin_amdgcn_mfma_f32_16x16x32_bf16(af[i], bg[j], acc[i][j], 0, 0, 0);
        }
        __syncthreads();
    }

    // Epilogue: C/D layout col = lane&15, row = quad*4 + reg.
#pragma unroll
    for (int i = 0; i < 4; ++i) {
#pragma unroll
        for (int j = 0; j < 8; ++j) {
            int col = tn * 256 + wn * 128 + j * 16 + l16;
#pragma unroll
            for (int r = 0; r < 4; ++r) {
                int row = tm * 128 + wm * 64 + i * 16 + quad * 4 + r;
                C[(size_t)row * N_ + col] = acc[i][j][r];
            }
        }
    }
}

extern "C" void kernel_launch(void* const* d_in, const int* in_sizes, int n_in,
                              void* d_out, int out_size, void* d_ws, size_t ws_size,
                              hipStream_t stream) {
    const float* x   = (const float*)d_in[0];   // [L, D]
    const float* xml = (const float*)d_in[1];   // [D]
    const float* fp  = (const float*)d_in[2];   // [D]
    const float* W   = (const float*)d_in[3];   // [D, D]
    float* out = (float*)d_out;                 // [L, D] fp32

    unsigned short* xmix = (unsigned short*)d_ws;                                      // 32 MB
    unsigned short* Wb   = (unsigned short*)((char*)d_ws + (size_t)L_SEQ * DIMN * 2);  // 8 MB
    float* carry = (float*)((char*)d_ws + (size_t)L_SEQ * DIMN * 2 + (size_t)DIMN * DIMN * 2); // 1 MB

    stage1<<<256 + DIMN * DIMN / 4 / 256, 256, 0, stream>>>(x, fp, W, carry, Wb);
    carry_prefix<<<DIMN / 64, 64, 0, stream>>>(fp, xml, carry);
    scan_apply<<<256, 256, 0, stream>>>(x, fp, carry, xmix);
    gemm_bt<<<dim3(L_SEQ / 128, DIMN / 256), 256, 0, stream>>>(xmix, Wb, out);
}